// Round 10
// baseline (160.348 us; speedup 1.0000x reference)
//
#include <hip/hip_runtime.h>
#include <hip/hip_bf16.h>

#define BATCH 8
#define CTX   2048
#define EMB   1024
#define HD    128
#define VSTR  2080   // Vt row stride (elems)

using bf16x8 = __attribute__((ext_vector_type(8))) short;
using fx4    = __attribute__((ext_vector_type(4))) float;

__device__ __forceinline__ ushort f2bf(float f) {
    union { float f; unsigned u; } v; v.f = f;
    unsigned u = v.u;
    u += 0x7fffu + ((u >> 16) & 1u);   // RNE
    return (ushort)(u >> 16);
}

__device__ __forceinline__ unsigned cvtpk(float a, float b) {
    unsigned r;
    asm("v_cvt_pk_bf16_f32 %0, %1, %2" : "=v"(r) : "v"(a), "v"(b));
    return r;
}

__device__ __forceinline__ void gload16(const void* g, void* l) {
    __builtin_amdgcn_global_load_lds(
        (const __attribute__((address_space(1))) unsigned*)g,
        (__attribute__((address_space(3))) unsigned*)l, 16, 0, 0);
}

// ---------------- kernel 1: W (E,H) fp32 -> Wt (3,H,E) bf16 ----------------
__global__ void wt_kernel(const float* __restrict__ Wq, const float* __restrict__ Wk,
                          const float* __restrict__ Wv, ushort* __restrict__ Wt) {
    int idx = blockIdx.x * blockDim.x + threadIdx.x;      // [3][HD][EMB]
    int e = idx % EMB;
    int h = (idx / EMB) % HD;
    int w = idx / (EMB * HD);
    const float* W = (w == 0) ? Wq : (w == 1) ? Wk : Wv;
    Wt[idx] = f2bf(W[e * HD + h]);
}

// ---------------- kernel 2: barrier-free register-fragment projection -------
// dim3(512,2) x 256 thr (4 waves). Wave owns a private 32x48 output tile
// (cols = by*192 + wave*48 + n*16). Operands global->register, 2-deep reg
// double-buffer, all indices static. No LDS, no barriers -> pure TLP latency
// hiding at ~12-16 waves/CU. NO waves-per-EU clause (round-9 NaN suspect).
__global__ __launch_bounds__(256) void proj_kernel(
        const float* __restrict__ x, const ushort* __restrict__ Wt,
        ushort* __restrict__ q, ushort* __restrict__ k, ushort* __restrict__ vt) {
    const int t    = threadIdx.x;
    const int wave = t >> 6;
    const int lane = t & 63;
    const int lo = lane & 15, hi = lane >> 4;
    const int brow = blockIdx.x * 32;
    const int bcol = blockIdx.y * 192;

    // per-lane operand pointers (k advances 32 elems/iter)
    const float*  a0p = x + (size_t)(brow + lo) * EMB + hi * 8;          // rows lo
    const float*  a1p = a0p + (size_t)16 * EMB;                          // rows 16+lo
    const ushort* b0p = Wt + (size_t)(bcol + wave * 48 + lo) * EMB + hi * 8;
    const ushort* b1p = b0p + (size_t)16 * EMB;
    const ushort* b2p = b0p + (size_t)32 * EMB;

    fx4 acc[2][3];
#pragma unroll
    for (int m2 = 0; m2 < 2; m2++)
#pragma unroll
        for (int n = 0; n < 3; n++) acc[m2][n] = fx4{0.f, 0.f, 0.f, 0.f};

    fx4    ab[2][4];   // A fp32: [buf][m2*2 + half]
    bf16x8 bb[2][3];   // B bf16: [buf][n]

    // prefetch it=0
    ab[0][0] = *(const fx4*)(a0p);     ab[0][1] = *(const fx4*)(a0p + 4);
    ab[0][2] = *(const fx4*)(a1p);     ab[0][3] = *(const fx4*)(a1p + 4);
    bb[0][0] = *(const bf16x8*)(b0p);
    bb[0][1] = *(const bf16x8*)(b1p);
    bb[0][2] = *(const bf16x8*)(b2p);

#pragma unroll
    for (int it = 0; it < 32; ++it) {
        const int cur = it & 1, nxt = cur ^ 1;
        if (it + 1 < 32) {
            const int off = (it + 1) * 32;
            ab[nxt][0] = *(const fx4*)(a0p + off);
            ab[nxt][1] = *(const fx4*)(a0p + off + 4);
            ab[nxt][2] = *(const fx4*)(a1p + off);
            ab[nxt][3] = *(const fx4*)(a1p + off + 4);
            bb[nxt][0] = *(const bf16x8*)(b0p + off);
            bb[nxt][1] = *(const bf16x8*)(b1p + off);
            bb[nxt][2] = *(const bf16x8*)(b2p + off);
        }
        bf16x8 af[2];
#pragma unroll
        for (int m2 = 0; m2 < 2; m2++) {
            union { unsigned u[4]; bf16x8 v; } pk;
            pk.u[0] = cvtpk(ab[cur][m2 * 2][0], ab[cur][m2 * 2][1]);
            pk.u[1] = cvtpk(ab[cur][m2 * 2][2], ab[cur][m2 * 2][3]);
            pk.u[2] = cvtpk(ab[cur][m2 * 2 + 1][0], ab[cur][m2 * 2 + 1][1]);
            pk.u[3] = cvtpk(ab[cur][m2 * 2 + 1][2], ab[cur][m2 * 2 + 1][3]);
            af[m2] = pk.v;
        }
#pragma unroll
        for (int n = 0; n < 3; n++)
#pragma unroll
            for (int m2 = 0; m2 < 2; m2++)
                acc[m2][n] = __builtin_amdgcn_mfma_f32_16x16x32_bf16(af[m2], bb[cur][n], acc[m2][n], 0, 0, 0);
    }

    const float qscale = 0.03125f;   // 1/sqrt(1024)
#pragma unroll
    for (int n = 0; n < 3; n++) {
        const int col = bcol + wave * 48 + n * 16 + lo;
        const int bnn = col >> 7;
        const int cc  = col & 127;
#pragma unroll
        for (int m2 = 0; m2 < 2; m2++) {
#pragma unroll
            for (int j = 0; j < 4; j++) {
                const int r = brow + m2 * 16 + hi * 4 + j;
                if (bnn == 0)      q[(size_t)r * HD + cc] = f2bf(acc[m2][n][j] * qscale);
                else if (bnn == 1) k[(size_t)r * HD + cc] = f2bf(acc[m2][n][j]);
                else {
                    const int bb2 = r >> 11, ccc = r & (CTX - 1);
                    vt[((size_t)bb2 * HD + cc) * VSTR + ccc] = f2bf(acc[m2][n][j]);
                }
            }
        }
    }
}

// ---------------- kernel 3: causal flash attention (32 q-rows, 4 waves) -----
// 512 blocks x 4 waves = 2048 waves (2/SIMD, 2 blocks/CU). wq = q 16-row
// group, w = kv column half. K/V dbuf staged via global_load_lds; single
// barrier per tile (stage-after-barrier). Defer-max softmax; LDS merge.
__global__ __launch_bounds__(256) void attn_kernel(
        const ushort* __restrict__ q, const ushort* __restrict__ k,
        const ushort* __restrict__ vt, float* __restrict__ out) {
    __shared__ __align__(16) char Ks[2][16384];   // [kv 64][hd 128] bf16, swizzled
    __shared__ __align__(16) char Vs[2][16384];   // [h 128][kv 64] bf16, swizzled
    __shared__ __align__(16) char p_lds[4][1024]; // per-wave P [16][32] bf16

    const int id   = blockIdx.x;
    const int b    = id & 7;                      // one batch per XCD
    const int pos  = id >> 3;                     // 0..63
    const int qt   = (pos < 32) ? (63 - pos) : (pos - 32);  // serpentine balance
    const int t    = threadIdx.x;
    const int wave = t >> 6;
    const int lane = t & 63;
    const int lo = lane & 15, hi = lane >> 4;
    const int wq = wave & 1, w = wave >> 1;
    const int q0 = qt * 32 + wq * 16;

    const ushort* qb = q  + (size_t)b * CTX * HD;
    const ushort* kb = k  + (size_t)b * CTX * HD;
    const ushort* vb = vt + (size_t)b * HD * VSTR;

    bf16x8 qf[4];
#pragma unroll
    for (int ks = 0; ks < 4; ks++)
        qf[ks] = *(const bf16x8*)(qb + (q0 + lo) * HD + ks * 32 + hi * 8);

    fx4 o[8];
#pragma unroll
    for (int h = 0; h < 8; h++) o[h] = fx4{0.f, 0.f, 0.f, 0.f};
    float m[4], l[4];
#pragma unroll
    for (int j = 0; j < 4; j++) { m[j] = 0.f; l[j] = 0.f; }

#define STAGE(bi, kv0_) do {                                                   \
    _Pragma("unroll")                                                          \
    for (int r = 0; r < 4; ++r) {                                              \
        const int row = r * 16 + (t >> 4);                                     \
        gload16(kb + (size_t)((kv0_) + row) * HD + (((t & 15) ^ (row & 7)) << 3), \
                Ks[bi] + r * 4096 + wave * 1024);                              \
    }                                                                          \
    _Pragma("unroll")                                                          \
    for (int r = 0; r < 4; ++r) {                                              \
        const int row = r * 32 + (t >> 3);                                     \
        gload16(vb + (size_t)row * VSTR + (kv0_) + (((t & 7) ^ (row & 7)) << 3), \
                Vs[bi] + r * 4096 + wave * 1024);                              \
    }                                                                          \
} while (0)

    const int nkv = qt / 2 + 1;
    STAGE(0, 0);
    for (int it = 0; it < nkv; ++it) {
        asm volatile("s_waitcnt vmcnt(0)" ::: "memory");   // stage(it) done
        __builtin_amdgcn_sched_barrier(0);
        __builtin_amdgcn_s_barrier();                      // visible to all waves
        __builtin_amdgcn_sched_barrier(0);
        if (it + 1 < nkv) STAGE((it + 1) & 1, (it + 1) * 64);

        const char* Kb = Ks[it & 1];
        const char* Vb = Vs[it & 1];
        const int kv0 = it * 64;

        // ---- S = Q K^T, this wave's 32 kv columns ----
        fx4 s[2];
        s[0] = fx4{0.f, 0.f, 0.f, 0.f};
        s[1] = fx4{0.f, 0.f, 0.f, 0.f};
        __builtin_amdgcn_s_setprio(1);
#pragma unroll
        for (int n2 = 0; n2 < 2; n2++) {
            const int row = w * 32 + n2 * 16 + lo;
            const unsigned sw = (unsigned)((row & 7) << 4);
#pragma unroll
            for (int ks = 0; ks < 4; ks++) {
                bf16x8 kf = *(const bf16x8*)(Kb + row * 256 + ((ks * 64 + hi * 16) ^ sw));
                s[n2] = __builtin_amdgcn_mfma_f32_16x16x32_bf16(qf[ks], kf, s[n2], 0, 0, 0);
            }
        }
        __builtin_amdgcn_s_setprio(0);

        const bool diag = (kv0 + 64 > q0);
        // ---- mask + defer-max overflow check (lane-local) ----
        float pmax[4];
        int allok = 1;
#pragma unroll
        for (int j = 0; j < 4; j++) {
            const int r = q0 + hi * 4 + j;
            if (diag) {
#pragma unroll
                for (int n2 = 0; n2 < 2; n2++)
                    if ((kv0 + w * 32 + n2 * 16 + lo) > r) s[n2][j] = -INFINITY;
            }
            pmax[j] = fmaxf(s[0][j], s[1][j]);
            allok &= (pmax[j] <= m[j] + 16.0f);
        }
        if (!__all(allok)) {
            // slow path (rare): full cross-lane max + rescale
#pragma unroll
            for (int j = 0; j < 4; j++) {
                float mx = pmax[j];
                mx = fmaxf(mx, __shfl_xor(mx, 1));
                mx = fmaxf(mx, __shfl_xor(mx, 2));
                mx = fmaxf(mx, __shfl_xor(mx, 4));
                mx = fmaxf(mx, __shfl_xor(mx, 8));
                const float mn = fmaxf(m[j], mx);
                const float f  = __expf(m[j] - mn);
                l[j] *= f;
#pragma unroll
                for (int h = 0; h < 8; h++) o[h][j] *= f;
                m[j] = mn;
            }
        }
        // ---- fast exp + lane-local l + P pack ----
#pragma unroll
        for (int j = 0; j < 4; j++) {
            float sum = 0.f;
#pragma unroll
            for (int n2 = 0; n2 < 2; n2++) {
                const float pv = __expf(s[n2][j] - m[j]);
                s[n2][j] = pv;
                sum += pv;
            }
            l[j] += sum;
            const int row = hi * 4 + j;
            const unsigned sw = (unsigned)((row & 3) << 4);
#pragma unroll
            for (int n2 = 0; n2 < 2; n2++) {
                const unsigned cb = (unsigned)((n2 * 16 + lo) * 2);
                *(ushort*)(p_lds[wave] + row * 64 + (cb ^ sw)) = f2bf(s[n2][j]);
            }
        }
        asm volatile("" ::: "memory");
        // ---- PV: A = P (16x32), B = this wave's Vt col half ----
        bf16x8 pa = *(const bf16x8*)(p_lds[wave] + lo * 64 + ((hi * 16) ^ ((lo & 3) << 4)));
        __builtin_amdgcn_s_setprio(1);
#pragma unroll
        for (int h = 0; h < 8; h++) {
            const int vr = h * 16 + lo;
            bf16x8 vf = *(const bf16x8*)(Vb + vr * 128 + ((w * 64 + hi * 16) ^ ((vr & 7) << 4)));
            o[h] = __builtin_amdgcn_mfma_f32_16x16x32_bf16(pa, vf, o[h], 0, 0, 0);
        }
        __builtin_amdgcn_s_setprio(0);
    }
#undef STAGE

    // ---- cross-lane l reduce (16-lane groups) ----
#pragma unroll
    for (int j = 0; j < 4; j++) {
        l[j] += __shfl_xor(l[j], 1);
        l[j] += __shfl_xor(l[j], 2);
        l[j] += __shfl_xor(l[j], 4);
        l[j] += __shfl_xor(l[j], 8);
    }

    // ---- merge the two kv-half partials per q-group (reuse Ks/Vs) ----
    float* oB  = (float*)Ks[0];    // [2][16][128]
    float* mlB = (float*)Vs[0];    // [2][2][16]
    __syncthreads();
    if (w == 1) {
#pragma unroll
        for (int j = 0; j < 4; j++) {
            const int row = hi * 4 + j;
            if (lo == 0) { mlB[wq * 32 + row] = m[j]; mlB[wq * 32 + 16 + row] = l[j]; }
#pragma unroll
            for (int h = 0; h < 8; h++)
                oB[(wq * 16 + row) * 128 + h * 16 + lo] = o[h][j];
        }
    }
    __syncthreads();
    if (w == 0) {
        float* ob = out + ((size_t)b * CTX + q0) * HD;
#pragma unroll
        for (int j = 0; j < 4; j++) {
            const int row = hi * 4 + j;
            const float mB = mlB[wq * 32 + row], lB = mlB[wq * 32 + 16 + row];
            const float mt = fmaxf(m[j], mB);
            const float fA = __expf(m[j] - mt);
            const float fB = __expf(mB - mt);
            const float inv = 1.0f / (l[j] * fA + lB * fB);
#pragma unroll
            for (int h = 0; h < 8; h++)
                ob[row * HD + h * 16 + lo] =
                    (o[h][j] * fA + oB[(wq * 16 + row) * 128 + h * 16 + lo] * fB) * inv;
        }
    }
}

extern "C" void kernel_launch(void* const* d_in, const int* in_sizes, int n_in,
                              void* d_out, int out_size, void* d_ws, size_t ws_size,
                              hipStream_t stream) {
    const float* x  = (const float*)d_in[0];
    const float* Wq = (const float*)d_in[1];
    const float* Wk = (const float*)d_in[2];
    const float* Wv = (const float*)d_in[3];

    // ws: Wt 768KB | q 4MB | k 4MB | Vt (padded) 4.06MB
    ushort* Wt = (ushort*)d_ws;
    ushort* qw = (ushort*)((char*)d_ws + 786432);
    ushort* kw = qw + (size_t)BATCH * CTX * HD;
    ushort* vw = kw + (size_t)BATCH * CTX * HD;

    wt_kernel<<<(3 * HD * EMB) / 256, 256, 0, stream>>>(Wq, Wk, Wv, Wt);
    proj_kernel<<<dim3(512, 2), 256, 0, stream>>>(x, Wt, qw, kw, vw);
    attn_kernel<<<512, 256, 0, stream>>>(qw, kw, vw, (float*)d_out);
}

// Round 11
// 90.267 us; speedup vs baseline: 1.7764x; 1.7764x over previous
//
#include <hip/hip_runtime.h>
#include <hip/hip_bf16.h>

#define BATCH 8
#define CTX   2048
#define EMB   1024
#define HD    128
#define VSTR  2080   // Vt row stride (elems)

using bf16x8 = __attribute__((ext_vector_type(8))) short;
using fx4    = __attribute__((ext_vector_type(4))) float;

__device__ __forceinline__ ushort f2bf(float f) {
    union { float f; unsigned u; } v; v.f = f;
    unsigned u = v.u;
    u += 0x7fffu + ((u >> 16) & 1u);   // RNE
    return (ushort)(u >> 16);
}

__device__ __forceinline__ unsigned cvtpk(float a, float b) {
    unsigned r;
    asm("v_cvt_pk_bf16_f32 %0, %1, %2" : "=v"(r) : "v"(a), "v"(b));
    return r;
}

__device__ __forceinline__ void gload16(const void* g, void* l) {
    __builtin_amdgcn_global_load_lds(
        (const __attribute__((address_space(1))) unsigned*)g,
        (__attribute__((address_space(3))) unsigned*)l, 16, 0, 0);
}

// ---------------- kernel 1: W (E,H) fp32 -> Wt (3,H,E) bf16 ----------------
__global__ void wt_kernel(const float* __restrict__ Wq, const float* __restrict__ Wk,
                          const float* __restrict__ Wv, ushort* __restrict__ Wt) {
    int idx = blockIdx.x * blockDim.x + threadIdx.x;      // [3][HD][EMB]
    int e = idx % EMB;
    int h = (idx / EMB) % HD;
    int w = idx / (EMB * HD);
    const float* W = (w == 0) ? Wq : (w == 1) ? Wk : Wv;
    Wt[idx] = f2bf(W[e * HD + h]);
}

// ---------------- kernel 2: m97-pattern projection, high-TLP tiling ---------
// BM=32, BN=192, BK=64; grid (512,2) = 1024 blocks = 4 blocks/CU (16 waves).
// Single-buffered LDS 32KB, global_load_lds staging, 2 barriers per K-step —
// barrier-drain stall hidden by cross-block TLP (m97/m114). Staging + read
// swizzles copied from the verified round-2 kernel (conflict-free).
__global__ __launch_bounds__(256) void proj_kernel(
        const float* __restrict__ x, const ushort* __restrict__ Wt,
        ushort* __restrict__ q, ushort* __restrict__ k, ushort* __restrict__ vt) {
    __shared__ __align__(16) float  As[32 * 64];    // 8 KB
    __shared__ __align__(16) ushort Bs[192 * 64];   // 24 KB

    const int t    = threadIdx.x;
    const int wave = t >> 6;
    const int lane = t & 63;
    const int lo = lane & 15, hi = lane >> 4;
    const int brow = blockIdx.x * 32;
    const int bcol = blockIdx.y * 192;

    const char* Ab = (const char*)As;
    const char* Bb = (const char*)Bs;

    fx4 acc[2][3];
#pragma unroll
    for (int m2 = 0; m2 < 2; m2++)
#pragma unroll
        for (int n = 0; n < 3; n++) acc[m2][n] = fx4{0.f, 0.f, 0.f, 0.f};

    // staging geometry (16B chunks; XOR-pre-swizzled global source, linear LDS)
    const int arow_s = t >> 4;                              // 0..15
    const int acol_s = ((t & 15) ^ (arow_s & 7)) << 2;      // f32 elems
    const int brow_s = t >> 3;                              // 0..31
    const int bcol_s = ((t & 7) ^ (brow_s & 7)) << 3;       // bf16 elems
    const int ldsbase = wave * 1024;                        // bytes (+ lane*16)

    for (int k0 = 0; k0 < EMB; k0 += 64) {
#pragma unroll
        for (int r = 0; r < 2; r++)
            gload16(x + (size_t)(brow + r * 16 + arow_s) * EMB + k0 + acol_s,
                    (char*)As + r * 4096 + ldsbase);
#pragma unroll
        for (int r = 0; r < 6; r++)
            gload16(Wt + (size_t)(bcol + r * 32 + brow_s) * EMB + k0 + bcol_s,
                    (char*)Bs + r * 4096 + ldsbase);
        __syncthreads();

#pragma unroll
        for (int ks = 0; ks < 2; ks++) {
            bf16x8 af[2], bfr[3];
#pragma unroll
            for (int m2 = 0; m2 < 2; m2++) {
                const int rowA = m2 * 16 + lo;
                const unsigned sw = (rowA & 7) << 4;
                const unsigned ub = rowA * 256 + ks * 128 + hi * 32;
                fx4 a0 = *(const fx4*)(Ab + (ub ^ sw));
                fx4 a1 = *(const fx4*)(Ab + ((ub + 16) ^ sw));
                union { unsigned u[4]; bf16x8 v; } pk;
                pk.u[0] = cvtpk(a0[0], a0[1]);
                pk.u[1] = cvtpk(a0[2], a0[3]);
                pk.u[2] = cvtpk(a1[0], a1[1]);
                pk.u[3] = cvtpk(a1[2], a1[3]);
                af[m2] = pk.v;
            }
#pragma unroll
            for (int n = 0; n < 3; n++) {
                const int rowB = wave * 48 + n * 16 + lo;
                const unsigned ub = rowB * 128 + ks * 64 + hi * 16;
                bfr[n] = *(const bf16x8*)(Bb + (ub ^ ((rowB & 7) << 4)));
            }
#pragma unroll
            for (int m2 = 0; m2 < 2; m2++)
#pragma unroll
                for (int n = 0; n < 3; n++)
                    acc[m2][n] = __builtin_amdgcn_mfma_f32_16x16x32_bf16(af[m2], bfr[n], acc[m2][n], 0, 0, 0);
        }
        __syncthreads();
    }

    const float qscale = 0.03125f;   // 1/sqrt(1024)
#pragma unroll
    for (int n = 0; n < 3; n++) {
        const int col = bcol + wave * 48 + n * 16 + lo;
        const int bnn = col >> 7;
        const int cc  = col & 127;
#pragma unroll
        for (int m2 = 0; m2 < 2; m2++) {
#pragma unroll
            for (int j = 0; j < 4; j++) {
                const int r = brow + m2 * 16 + hi * 4 + j;
                if (bnn == 0)      q[(size_t)r * HD + cc] = f2bf(acc[m2][n][j] * qscale);
                else if (bnn == 1) k[(size_t)r * HD + cc] = f2bf(acc[m2][n][j]);
                else {
                    const int bb2 = r >> 11, ccc = r & (CTX - 1);
                    vt[((size_t)bb2 * HD + cc) * VSTR + ccc] = f2bf(acc[m2][n][j]);
                }
            }
        }
    }
}

// ---------------- kernel 3: causal flash attention (32 q-rows, 4 waves) -----
// 512 blocks x 4 waves = 2048 waves (2/SIMD, 2 blocks/CU). wq = q 16-row
// group, w = kv column half. K/V dbuf staged via global_load_lds; single
// barrier per tile (stage-after-barrier). Defer-max softmax; LDS merge.
__global__ __launch_bounds__(256) void attn_kernel(
        const ushort* __restrict__ q, const ushort* __restrict__ k,
        const ushort* __restrict__ vt, float* __restrict__ out) {
    __shared__ __align__(16) char Ks[2][16384];   // [kv 64][hd 128] bf16, swizzled
    __shared__ __align__(16) char Vs[2][16384];   // [h 128][kv 64] bf16, swizzled
    __shared__ __align__(16) char p_lds[4][1024]; // per-wave P [16][32] bf16

    const int id   = blockIdx.x;
    const int b    = id & 7;                      // one batch per XCD
    const int pos  = id >> 3;                     // 0..63
    const int qt   = (pos < 32) ? (63 - pos) : (pos - 32);  // serpentine balance
    const int t    = threadIdx.x;
    const int wave = t >> 6;
    const int lane = t & 63;
    const int lo = lane & 15, hi = lane >> 4;
    const int wq = wave & 1, w = wave >> 1;
    const int q0 = qt * 32 + wq * 16;

    const ushort* qb = q  + (size_t)b * CTX * HD;
    const ushort* kb = k  + (size_t)b * CTX * HD;
    const ushort* vb = vt + (size_t)b * HD * VSTR;

    bf16x8 qf[4];
#pragma unroll
    for (int ks = 0; ks < 4; ks++)
        qf[ks] = *(const bf16x8*)(qb + (q0 + lo) * HD + ks * 32 + hi * 8);

    fx4 o[8];
#pragma unroll
    for (int h = 0; h < 8; h++) o[h] = fx4{0.f, 0.f, 0.f, 0.f};
    float m[4], l[4];
#pragma unroll
    for (int j = 0; j < 4; j++) { m[j] = 0.f; l[j] = 0.f; }

#define STAGE(bi, kv0_) do {                                                   \
    _Pragma("unroll")                                                          \
    for (int r = 0; r < 4; ++r) {                                              \
        const int row = r * 16 + (t >> 4);                                     \
        gload16(kb + (size_t)((kv0_) + row) * HD + (((t & 15) ^ (row & 7)) << 3), \
                Ks[bi] + r * 4096 + wave * 1024);                              \
    }                                                                          \
    _Pragma("unroll")                                                          \
    for (int r = 0; r < 4; ++r) {                                              \
        const int row = r * 32 + (t >> 3);                                     \
        gload16(vb + (size_t)row * VSTR + (kv0_) + (((t & 7) ^ (row & 7)) << 3), \
                Vs[bi] + r * 4096 + wave * 1024);                              \
    }                                                                          \
} while (0)

    const int nkv = qt / 2 + 1;
    STAGE(0, 0);
    for (int it = 0; it < nkv; ++it) {
        asm volatile("s_waitcnt vmcnt(0)" ::: "memory");   // stage(it) done
        __builtin_amdgcn_sched_barrier(0);
        __builtin_amdgcn_s_barrier();                      // visible to all waves
        __builtin_amdgcn_sched_barrier(0);
        if (it + 1 < nkv) STAGE((it + 1) & 1, (it + 1) * 64);

        const char* Kb = Ks[it & 1];
        const char* Vb = Vs[it & 1];
        const int kv0 = it * 64;

        // ---- S = Q K^T, this wave's 32 kv columns ----
        fx4 s[2];
        s[0] = fx4{0.f, 0.f, 0.f, 0.f};
        s[1] = fx4{0.f, 0.f, 0.f, 0.f};
        __builtin_amdgcn_s_setprio(1);
#pragma unroll
        for (int n2 = 0; n2 < 2; n2++) {
            const int row = w * 32 + n2 * 16 + lo;
            const unsigned sw = (unsigned)((row & 7) << 4);
#pragma unroll
            for (int ks = 0; ks < 4; ks++) {
                bf16x8 kf = *(const bf16x8*)(Kb + row * 256 + ((ks * 64 + hi * 16) ^ sw));
                s[n2] = __builtin_amdgcn_mfma_f32_16x16x32_bf16(qf[ks], kf, s[n2], 0, 0, 0);
            }
        }
        __builtin_amdgcn_s_setprio(0);

        const bool diag = (kv0 + 64 > q0);
        // ---- mask + defer-max overflow check (lane-local) ----
        float pmax[4];
        int allok = 1;
#pragma unroll
        for (int j = 0; j < 4; j++) {
            const int r = q0 + hi * 4 + j;
            if (diag) {
#pragma unroll
                for (int n2 = 0; n2 < 2; n2++)
                    if ((kv0 + w * 32 + n2 * 16 + lo) > r) s[n2][j] = -INFINITY;
            }
            pmax[j] = fmaxf(s[0][j], s[1][j]);
            allok &= (pmax[j] <= m[j] + 16.0f);
        }
        if (!__all(allok)) {
            // slow path (rare): full cross-lane max + rescale
#pragma unroll
            for (int j = 0; j < 4; j++) {
                float mx = pmax[j];
                mx = fmaxf(mx, __shfl_xor(mx, 1));
                mx = fmaxf(mx, __shfl_xor(mx, 2));
                mx = fmaxf(mx, __shfl_xor(mx, 4));
                mx = fmaxf(mx, __shfl_xor(mx, 8));
                const float mn = fmaxf(m[j], mx);
                const float f  = __expf(m[j] - mn);
                l[j] *= f;
#pragma unroll
                for (int h = 0; h < 8; h++) o[h][j] *= f;
                m[j] = mn;
            }
        }
        // ---- fast exp + lane-local l + P pack ----
#pragma unroll
        for (int j = 0; j < 4; j++) {
            float sum = 0.f;
#pragma unroll
            for (int n2 = 0; n2 < 2; n2++) {
                const float pv = __expf(s[n2][j] - m[j]);
                s[n2][j] = pv;
                sum += pv;
            }
            l[j] += sum;
            const int row = hi * 4 + j;
            const unsigned sw = (unsigned)((row & 3) << 4);
#pragma unroll
            for (int n2 = 0; n2 < 2; n2++) {
                const unsigned cb = (unsigned)((n2 * 16 + lo) * 2);
                *(ushort*)(p_lds[wave] + row * 64 + (cb ^ sw)) = f2bf(s[n2][j]);
            }
        }
        asm volatile("" ::: "memory");
        // ---- PV: A = P (16x32), B = this wave's Vt col half ----
        bf16x8 pa = *(const bf16x8*)(p_lds[wave] + lo * 64 + ((hi * 16) ^ ((lo & 3) << 4)));
        __builtin_amdgcn_s_setprio(1);
#pragma unroll
        for (int h = 0; h < 8; h++) {
            const int vr = h * 16 + lo;
            bf16x8 vf = *(const bf16x8*)(Vb + vr * 128 + ((w * 64 + hi * 16) ^ ((vr & 7) << 4)));
            o[h] = __builtin_amdgcn_mfma_f32_16x16x32_bf16(pa, vf, o[h], 0, 0, 0);
        }
        __builtin_amdgcn_s_setprio(0);
    }
#undef STAGE

    // ---- cross-lane l reduce (16-lane groups) ----
#pragma unroll
    for (int j = 0; j < 4; j++) {
        l[j] += __shfl_xor(l[j], 1);
        l[j] += __shfl_xor(l[j], 2);
        l[j] += __shfl_xor(l[j], 4);
        l[j] += __shfl_xor(l[j], 8);
    }

    // ---- merge the two kv-half partials per q-group (reuse Ks/Vs) ----
    float* oB  = (float*)Ks[0];    // [2][16][128]
    float* mlB = (float*)Vs[0];    // [2][2][16]
    __syncthreads();
    if (w == 1) {
#pragma unroll
        for (int j = 0; j < 4; j++) {
            const int row = hi * 4 + j;
            if (lo == 0) { mlB[wq * 32 + row] = m[j]; mlB[wq * 32 + 16 + row] = l[j]; }
#pragma unroll
            for (int h = 0; h < 8; h++)
                oB[(wq * 16 + row) * 128 + h * 16 + lo] = o[h][j];
        }
    }
    __syncthreads();
    if (w == 0) {
        float* ob = out + ((size_t)b * CTX + q0) * HD;
#pragma unroll
        for (int j = 0; j < 4; j++) {
            const int row = hi * 4 + j;
            const float mB = mlB[wq * 32 + row], lB = mlB[wq * 32 + 16 + row];
            const float mt = fmaxf(m[j], mB);
            const float fA = __expf(m[j] - mt);
            const float fB = __expf(mB - mt);
            const float inv = 1.0f / (l[j] * fA + lB * fB);
#pragma unroll
            for (int h = 0; h < 8; h++)
                ob[row * HD + h * 16 + lo] =
                    (o[h][j] * fA + oB[(wq * 16 + row) * 128 + h * 16 + lo] * fB) * inv;
        }
    }
}

extern "C" void kernel_launch(void* const* d_in, const int* in_sizes, int n_in,
                              void* d_out, int out_size, void* d_ws, size_t ws_size,
                              hipStream_t stream) {
    const float* x  = (const float*)d_in[0];
    const float* Wq = (const float*)d_in[1];
    const float* Wk = (const float*)d_in[2];
    const float* Wv = (const float*)d_in[3];

    // ws: Wt 768KB | q 4MB | k 4MB | Vt (padded) 4.06MB
    ushort* Wt = (ushort*)d_ws;
    ushort* qw = (ushort*)((char*)d_ws + 786432);
    ushort* kw = qw + (size_t)BATCH * CTX * HD;
    ushort* vw = kw + (size_t)BATCH * CTX * HD;

    wt_kernel<<<(3 * HD * EMB) / 256, 256, 0, stream>>>(Wq, Wk, Wv, Wt);
    proj_kernel<<<dim3(512, 2), 256, 0, stream>>>(x, Wt, qw, kw, vw);
    attn_kernel<<<512, 256, 0, stream>>>(qw, kw, vw, (float*)d_out);
}